// Round 5
// baseline (1851.390 us; speedup 1.0000x reference)
//
#include <hip/hip_runtime.h>
#include <hip/hip_bf16.h>
#include <math.h>

#define N_NODES 100000
#define N_EDGES 1600000
#define IN_C    500
#define HID     256
#define OUT_C   40
#define K_ITERS 10
#define ALPHA   0.1f
#define LN_EPS  1e-5f

#define K1PAD   512
#define K2PAD   256

#define SCAN_CHUNK 1024
#define NBLK_SCAN  ((N_NODES + SCAN_CHUNK - 1) / SCAN_CHUNK)   // 98

typedef __attribute__((ext_vector_type(8))) short bf16x8;
typedef __attribute__((ext_vector_type(4))) float f32x4;

// ---------------------------------------------------------------------------
// fp32 -> bf16 hi/lo split (3-term Markidis; lo absorbs truncation error)
// ---------------------------------------------------------------------------
__device__ __forceinline__ void split2(float a, short& hi, short& lo) {
    const unsigned ua = __float_as_uint(a);
    hi = (short)(ua >> 16);
    const float r = a - __uint_as_float(ua & 0xffff0000u);
    lo = (short)(__float_as_uint(r) >> 16);
}

// ---------------------------------------------------------------------------
// degree count / dinv
// ---------------------------------------------------------------------------
__global__ void deg_count_kernel(const int* __restrict__ col, int* __restrict__ cnt, int e) {
    int i = blockIdx.x * blockDim.x + threadIdx.x;
    if (i < e) atomicAdd(&cnt[col[i]], 1);
}

__global__ void dinv_kernel(const int* __restrict__ cnt, float* __restrict__ dinv, int n) {
    int i = blockIdx.x * blockDim.x + threadIdx.x;
    if (i < n) dinv[i] = rsqrtf((float)cnt[i] + 1.0f);  // +1 = self loop
}

// ---------------------------------------------------------------------------
// 3-kernel exclusive scan of cnt[N] -> offs[N] (+ offs[N]=E)
// ---------------------------------------------------------------------------
__global__ __launch_bounds__(256) void scan_partial_kernel(const int* __restrict__ cnt,
                                                           int* __restrict__ bsum) {
    __shared__ int s[256];
    const int base = blockIdx.x * SCAN_CHUNK;
    const int t = threadIdx.x;
    int sum = 0;
    #pragma unroll
    for (int j = 0; j < 4; j++) {
        int idx = base + t * 4 + j;
        if (idx < N_NODES) sum += cnt[idx];
    }
    s[t] = sum;
    __syncthreads();
    for (int off = 128; off > 0; off >>= 1) {
        if (t < off) s[t] += s[t + off];
        __syncthreads();
    }
    if (t == 0) bsum[blockIdx.x] = s[0];
}

__global__ __launch_bounds__(128) void scan_bsum_kernel(int* __restrict__ bsum, int nblk) {
    __shared__ int s[128];
    const int t = threadIdx.x;
    const int orig = (t < nblk) ? bsum[t] : 0;
    s[t] = orig;
    __syncthreads();
    for (int off = 1; off < 128; off <<= 1) {
        int v = 0;
        if (t >= off) v = s[t - off];
        __syncthreads();
        s[t] += v;
        __syncthreads();
    }
    if (t < nblk) bsum[t] = s[t] - orig;   // exclusive
}

__global__ __launch_bounds__(256) void scan_final_kernel(const int* __restrict__ cnt,
                                                         const int* __restrict__ bsum,
                                                         int* __restrict__ offs) {
    __shared__ int s[256];
    const int base = blockIdx.x * SCAN_CHUNK;
    const int t = threadIdx.x;
    int v[4];
    int lsum = 0;
    #pragma unroll
    for (int j = 0; j < 4; j++) {
        int idx = base + t * 4 + j;
        v[j] = (idx < N_NODES) ? cnt[idx] : 0;
        lsum += v[j];
    }
    s[t] = lsum;
    __syncthreads();
    const int orig = lsum;
    for (int off = 1; off < 256; off <<= 1) {
        int u = 0;
        if (t >= off) u = s[t - off];
        __syncthreads();
        s[t] += u;
        __syncthreads();
    }
    int run = bsum[blockIdx.x] + (s[t] - orig);
    #pragma unroll
    for (int j = 0; j < 4; j++) {
        int idx = base + t * 4 + j;
        if (idx < N_NODES) offs[idx] = run;
        run += v[j];
    }
}

__global__ void set_total_kernel(int* __restrict__ offs) {
    if (threadIdx.x == 0 && blockIdx.x == 0) offs[N_NODES] = N_EDGES;
}

// ---------------------------------------------------------------------------
// CSR fill: group edges by target col; packed (src, weight-bits) int2
// ---------------------------------------------------------------------------
__global__ void csr_fill_kernel(const int* __restrict__ row, const int* __restrict__ col,
                                const float* __restrict__ dinv, const int* __restrict__ offs,
                                int* __restrict__ cursor, int2* __restrict__ csr_ew, int e) {
    int i = blockIdx.x * blockDim.x + threadIdx.x;
    if (i >= e) return;
    const int r = row[i], c = col[i];
    const int p = offs[c] + atomicAdd(&cursor[c], 1);
    csr_ew[p] = make_int2(r, __float_as_int(dinv[r] * dinv[c]));
}

// ---------------------------------------------------------------------------
// W [K,N] fp32 -> transposed hi/lo planes [N,Kpad]
// ---------------------------------------------------------------------------
__global__ __launch_bounds__(256) void wsplit_kernel(
    const float* __restrict__ W, short* __restrict__ hi, short* __restrict__ lo,
    int K, int Nn, int Kpad)
{
    const int idx = blockIdx.x * 256 + threadIdx.x;
    if (idx >= Nn * Kpad) return;
    const int n = idx / Kpad, k = idx - n * Kpad;
    const float v = (k < K) ? W[(size_t)k * Nn + n] : 0.0f;
    short h, l;
    split2(v, h, l);
    hi[idx] = h;
    lo[idx] = l;
}

// ---------------------------------------------------------------------------
// GEMM1 v3: REGISTER-DIRECT, no LDS, no barriers. Each lane loads its A
// fragment straight from X (fp32, split2 in-register) and B fragments
// straight from the L2-resident W planes. Rationale: staged versions tied
// twice at 228us with everything idle (Occ 19%, Mfma 14%) -- barrier-locked
// staging drains. W1 planes (512KB) are L2-resident; X has no intra-block
// reuse beyond the register fragment. Waves free-run; occupancy VGPR-bound.
// ---------------------------------------------------------------------------
#define GBM 64
#define GBN 256
#define GBK 32
#define NSTEP1 (K1PAD / GBK)   // 16
#define NSTEP2 (K2PAD / GBK)   // 8

__global__ __launch_bounds__(256, 4) void gemm1_fused_kernel(
    const float* __restrict__ X,
    const short* __restrict__ Bhi, const short* __restrict__ Blo,
    const float* __restrict__ bias, float* __restrict__ C, int M)
{
    const int tid  = threadIdx.x;
    const int wid  = tid >> 6, lane = tid & 63;
    const int wm   = wid >> 1, wn = wid & 1;
    const int fm   = lane & 15, fq = lane >> 4;
    const int row0 = blockIdx.x * GBM;

    // the 2 A-rows this lane feeds (tm=0,1); clamp for tail block
    const float* xp0 = X + (size_t)min(row0 + wm * 32 + fm,      M - 1) * IN_C;
    const float* xp1 = X + (size_t)min(row0 + wm * 32 + 16 + fm, M - 1) * IN_C;

    f32x4 acc[2][8] = {};

    for (int ks = 0; ks < NSTEP1; ks++) {
        const int kk = ks * GBK + fq * 8;   // this lane's k-segment

        // A fragments: 8 fp32 -> hi/lo bf16x8, per tm
        bf16x8 ah[2], al[2];
        {
            const float* xs[2] = { xp0, xp1 };
            #pragma unroll
            for (int tm = 0; tm < 2; tm++) {
                float v[8];
                if (kk + 8 <= IN_C) {
                    const float4 v0 = *(const float4*)(xs[tm] + kk);
                    const float4 v1 = *(const float4*)(xs[tm] + kk + 4);
                    v[0]=v0.x; v[1]=v0.y; v[2]=v0.z; v[3]=v0.w;
                    v[4]=v1.x; v[5]=v1.y; v[6]=v1.z; v[7]=v1.w;
                } else {
                    #pragma unroll
                    for (int j = 0; j < 8; j++)
                        v[j] = (kk + j < IN_C) ? xs[tm][kk + j] : 0.0f;
                }
                #pragma unroll
                for (int j = 0; j < 8; j++) {
                    short th, tl; split2(v[j], th, tl);
                    ah[tm][j] = th; al[tm][j] = tl;
                }
            }
        }

        #pragma unroll
        for (int tn = 0; tn < 8; tn++) {
            const int cc = wn * 128 + tn * 16 + fm;
            const bf16x8 bh = *(const bf16x8*)(Bhi + (size_t)cc * K1PAD + kk);
            const bf16x8 bl = *(const bf16x8*)(Blo + (size_t)cc * K1PAD + kk);
            #pragma unroll
            for (int tm = 0; tm < 2; tm++) {
                acc[tm][tn] = __builtin_amdgcn_mfma_f32_16x16x32_bf16(ah[tm], bh, acc[tm][tn], 0, 0, 0);
                acc[tm][tn] = __builtin_amdgcn_mfma_f32_16x16x32_bf16(ah[tm], bl, acc[tm][tn], 0, 0, 0);
                acc[tm][tn] = __builtin_amdgcn_mfma_f32_16x16x32_bf16(al[tm], bh, acc[tm][tn], 0, 0, 0);
            }
        }
    }

    // epilogue: C/D layout col=lane&15, row=fq*4+r
    #pragma unroll
    for (int tm = 0; tm < 2; tm++) {
        #pragma unroll
        for (int tn = 0; tn < 8; tn++) {
            const int gc = wn * 128 + tn * 16 + fm;
            const float bv = bias[gc];
            #pragma unroll
            for (int r = 0; r < 4; r++) {
                const int gr2 = row0 + wm * 32 + tm * 16 + fq * 4 + r;
                if (gr2 < M) {
                    float v = acc[tm][tn][r] + bv;
                    v = 0.5f * v * (1.0f + erff(v * 0.70710678118654752f));
                    C[(size_t)gr2 * 256 + gc] = v;
                }
            }
        }
    }
}

// ---------------------------------------------------------------------------
// GEMM2 v3: register-direct, no LDS/barriers. A planes (bf16, L3-resident)
// and W2 planes (256KB, L2-resident) loaded straight to fragments.
// ---------------------------------------------------------------------------
__global__ __launch_bounds__(256, 4) void gemm2_kernel(
    const short* __restrict__ Ahi, const short* __restrict__ Alo,
    const short* __restrict__ Bhi, const short* __restrict__ Blo,
    const float* __restrict__ bias, float* __restrict__ C, int M)
{
    const int tid  = threadIdx.x;
    const int wid  = tid >> 6, lane = tid & 63;
    const int wm   = wid >> 1, wn = wid & 1;
    const int fm   = lane & 15, fq = lane >> 4;
    const int row0 = blockIdx.x * GBM;

    const size_t r0 = (size_t)min(row0 + wm * 32 + fm,      M - 1) * K2PAD;
    const size_t r1 = (size_t)min(row0 + wm * 32 + 16 + fm, M - 1) * K2PAD;

    f32x4 acc[2][8] = {};

    for (int ks = 0; ks < NSTEP2; ks++) {
        const int kk = ks * GBK + fq * 8;

        bf16x8 ah[2], al[2];
        ah[0] = *(const bf16x8*)(Ahi + r0 + kk);
        al[0] = *(const bf16x8*)(Alo + r0 + kk);
        ah[1] = *(const bf16x8*)(Ahi + r1 + kk);
        al[1] = *(const bf16x8*)(Alo + r1 + kk);

        #pragma unroll
        for (int tn = 0; tn < 8; tn++) {
            const int cc = wn * 128 + tn * 16 + fm;
            const bf16x8 bh = *(const bf16x8*)(Bhi + (size_t)cc * K2PAD + kk);
            const bf16x8 bl = *(const bf16x8*)(Blo + (size_t)cc * K2PAD + kk);
            #pragma unroll
            for (int tm = 0; tm < 2; tm++) {
                acc[tm][tn] = __builtin_amdgcn_mfma_f32_16x16x32_bf16(ah[tm], bh, acc[tm][tn], 0, 0, 0);
                acc[tm][tn] = __builtin_amdgcn_mfma_f32_16x16x32_bf16(ah[tm], bl, acc[tm][tn], 0, 0, 0);
                acc[tm][tn] = __builtin_amdgcn_mfma_f32_16x16x32_bf16(al[tm], bh, acc[tm][tn], 0, 0, 0);
            }
        }
    }

    #pragma unroll
    for (int tm = 0; tm < 2; tm++) {
        #pragma unroll
        for (int tn = 0; tn < 8; tn++) {
            const int gc = wn * 128 + tn * 16 + fm;
            const float bv = bias[gc];
            #pragma unroll
            for (int r = 0; r < 4; r++) {
                const int gr2 = row0 + wm * 32 + tm * 16 + fq * 4 + r;
                if (gr2 < M) {
                    float v = acc[tm][tn][r] + bv;
                    v = 0.5f * v * (1.0f + erff(v * 0.70710678118654752f));
                    C[(size_t)gr2 * 256 + gc] = v;
                }
            }
        }
    }
}

// ---------------------------------------------------------------------------
// LayerNorm(256) -> bf16 hi/lo planes [M,256] (feeds GEMM2)
// ---------------------------------------------------------------------------
__global__ __launch_bounds__(256) void layernorm_split_kernel(
    const float* __restrict__ h, const float* __restrict__ g, const float* __restrict__ b,
    short* __restrict__ hi, short* __restrict__ lo, int nrows)
{
    const int wave = threadIdx.x >> 6;
    const int lane = threadIdx.x & 63;
    const int row  = blockIdx.x * 4 + wave;
    if (row >= nrows) return;

    const float* p = h + (size_t)row * HID;
    float v[4];
    float s = 0.0f;
    #pragma unroll
    for (int j = 0; j < 4; j++) { v[j] = p[lane + 64 * j]; s += v[j]; }
    #pragma unroll
    for (int off = 32; off > 0; off >>= 1) s += __shfl_xor(s, off);
    const float mu = s * (1.0f / 256.0f);

    float vs = 0.0f;
    #pragma unroll
    for (int j = 0; j < 4; j++) { float d = v[j] - mu; vs += d * d; }
    #pragma unroll
    for (int off = 32; off > 0; off >>= 1) vs += __shfl_xor(vs, off);
    const float rs = rsqrtf(vs * (1.0f / 256.0f) + LN_EPS);

    #pragma unroll
    for (int j = 0; j < 4; j++) {
        const int c = lane + 64 * j;
        const float o = (v[j] - mu) * rs * g[c] + b[c];
        short th, tl;
        split2(o, th, tl);
        hi[(size_t)row * HID + c] = th;
        lo[(size_t)row * HID + c] = tl;
    }
}

// ---------------------------------------------------------------------------
// Fused LayerNorm(256) + GEMM3 [256 x 40] + b3 -> h0.
// ---------------------------------------------------------------------------
__global__ __launch_bounds__(256) void ln_gemm3_kernel(
    const float* __restrict__ h, const float* __restrict__ g, const float* __restrict__ b,
    const float* __restrict__ W, const float* __restrict__ bias,
    float* __restrict__ C, int nrows)
{
    __shared__ float Ws[HID * OUT_C];   // 40 KB
    __shared__ float bs[OUT_C];
    __shared__ float rowbuf[4][HID];    // 4 KB

    for (int i = threadIdx.x; i < HID * OUT_C; i += 256) Ws[i] = W[i];
    if (threadIdx.x < OUT_C) bs[threadIdx.x] = bias[threadIdx.x];

    const int wave = threadIdx.x >> 6;
    const int lane = threadIdx.x & 63;
    const int row  = blockIdx.x * 4 + wave;
    const bool alive = (row < nrows);

    if (alive) {
        const float* p = h + (size_t)row * HID;
        float v[4];
        float s = 0.0f;
        #pragma unroll
        for (int j = 0; j < 4; j++) { v[j] = p[lane + 64 * j]; s += v[j]; }
        #pragma unroll
        for (int off = 32; off > 0; off >>= 1) s += __shfl_xor(s, off);
        const float mu = s * (1.0f / 256.0f);

        float vs = 0.0f;
        #pragma unroll
        for (int j = 0; j < 4; j++) { float d = v[j] - mu; vs += d * d; }
        #pragma unroll
        for (int off = 32; off > 0; off >>= 1) vs += __shfl_xor(vs, off);
        const float rs = rsqrtf(vs * (1.0f / 256.0f) + LN_EPS);

        #pragma unroll
        for (int j = 0; j < 4; j++) {
            const int c = lane + 64 * j;
            rowbuf[wave][c] = (v[j] - mu) * rs * g[c] + b[c];
        }
    }
    __syncthreads();   // Ws + rowbuf ready

    if (alive && lane < OUT_C) {
        float s = 0.0f;
        #pragma unroll 8
        for (int k = 0; k < HID; k++)
            s += rowbuf[wave][k] * Ws[k * OUT_C + lane];
        C[(size_t)row * OUT_C + lane] = s + bs[lane];
    }
}

// ---------------------------------------------------------------------------
// APPNP step (proven r3 version): one wave per node; 3-wide unrolled gather.
// ---------------------------------------------------------------------------
__global__ __launch_bounds__(256) void appnp_kernel(
    const int* __restrict__ offs, const int2* __restrict__ csr_ew,
    const float* __restrict__ dinv,
    const float* __restrict__ h, const float* __restrict__ h0,
    float* __restrict__ out)
{
    const int node = blockIdx.x * 4 + (threadIdx.x >> 6);
    if (node >= N_NODES) return;           // wave-uniform exit
    const int lane = threadIdx.x & 63;
    const int g = lane / 10;               // 0..6 (g==6 => lanes 60..63 idle)
    const int q = lane - g * 10;           // channel quad 0..9
    const bool act = (lane < 60);

    const int start = offs[node];
    const int end   = offs[node + 1];

    const float d = dinv[node];
    float4 hs  = make_float4(0.f, 0.f, 0.f, 0.f);
    float4 h0v = make_float4(0.f, 0.f, 0.f, 0.f);
    const size_t eidx = (size_t)node * OUT_C + (lane < 10 ? lane : 0) * 4;
    if (lane < 10) {
        hs  = *(const float4*)(h + eidx);
        h0v = *(const float4*)(h0 + eidx);
    }

    float ax = 0.0f, ay = 0.0f, az = 0.0f, aw = 0.0f;
    for (int e0 = start; e0 < end; e0 += 18) {
        const int ee0 = e0 + g, ee1 = ee0 + 6, ee2 = ee0 + 12;
        const bool a0 = act && (ee0 < end);
        const bool a1 = act && (ee1 < end);
        const bool a2 = act && (ee2 < end);
        const int2 ed0 = csr_ew[a0 ? ee0 : start];
        const int2 ed1 = csr_ew[a1 ? ee1 : start];
        const int2 ed2 = csr_ew[a2 ? ee2 : start];
        const float4 v0 = *(const float4*)(h + (size_t)ed0.x * OUT_C + q * 4);
        const float4 v1 = *(const float4*)(h + (size_t)ed1.x * OUT_C + q * 4);
        const float4 v2 = *(const float4*)(h + (size_t)ed2.x * OUT_C + q * 4);
        const float w0 = a0 ? __int_as_float(ed0.y) : 0.0f;
        const float w1 = a1 ? __int_as_float(ed1.y) : 0.0f;
        const float w2 = a2 ? __int_as_float(ed2.y) : 0.0f;
        ax += w0 * v0.x + w1 * v1.x + w2 * v2.x;
        ay += w0 * v0.y + w1 * v1.y + w2 * v2.y;
        az += w0 * v0.z + w1 * v1.z + w2 * v2.z;
        aw += w0 * v0.w + w1 * v1.w + w2 * v2.w;
    }

    // reduce over edge-groups: lanes {q, q+10, ..., q+50} -> lane q
    ax += __shfl(ax, lane + 30); ay += __shfl(ay, lane + 30);
    az += __shfl(az, lane + 30); aw += __shfl(aw, lane + 30);
    {
        const float bx = __shfl(ax, lane + 10), cx = __shfl(ax, lane + 20);
        const float by = __shfl(ay, lane + 10), cy = __shfl(ay, lane + 20);
        const float bz = __shfl(az, lane + 10), cz = __shfl(az, lane + 20);
        const float bw = __shfl(aw, lane + 10), cw = __shfl(aw, lane + 20);
        ax += bx + cx; ay += by + cy; az += bz + cz; aw += bw + cw;
    }

    if (lane < 10) {
        const float self = d * d;
        float4 o;
        o.x = (1.0f - ALPHA) * (ax + self * hs.x) + ALPHA * h0v.x;
        o.y = (1.0f - ALPHA) * (ay + self * hs.y) + ALPHA * h0v.y;
        o.z = (1.0f - ALPHA) * (az + self * hs.z) + ALPHA * h0v.z;
        o.w = (1.0f - ALPHA) * (aw + self * hs.w) + ALPHA * h0v.w;
        *(float4*)(out + eidx) = o;
    }
}

// ---------------------------------------------------------------------------
extern "C" void kernel_launch(void* const* d_in, const int* in_sizes, int n_in,
                              void* d_out, int out_size, void* d_ws, size_t ws_size,
                              hipStream_t stream) {
    const float* x   = (const float*)d_in[0];
    const int*   ei  = (const int*)d_in[1];
    const float* W1  = (const float*)d_in[2];
    const float* b1  = (const float*)d_in[3];
    const float* g1  = (const float*)d_in[4];
    const float* be1 = (const float*)d_in[5];
    const float* W2  = (const float*)d_in[6];
    const float* b2  = (const float*)d_in[7];
    const float* g2  = (const float*)d_in[8];
    const float* be2 = (const float*)d_in[9];
    const float* W3  = (const float*)d_in[10];
    const float* b3  = (const float*)d_in[11];
    float* out = (float*)d_out;

    const int* e_row = ei;
    const int* e_col = ei + N_EDGES;

    // ---- workspace layout (float units), regions aliased by liveness ----
    float* ws = (float*)d_ws;
    size_t off = 0;
    float* dinv = ws + off; off += N_NODES;
    int*   cnt  = (int*)(ws + off); off += N_NODES;
    int*   offs = (int*)(ws + off); off += N_NODES + 1;
    int*   bsum = (int*)(ws + off); off += 128 + 3;      // +3: keep 16B alignment downstream
    short* W1hi = (short*)(ws + off); off += 65536;      // 256*512 shorts
    short* W1lo = (short*)(ws + off); off += 65536;
    short* W2hi = (short*)(ws + off); off += 32768;      // 256*256 shorts
    short* W2lo = (short*)(ws + off); off += 32768;
    // Region B: t1 (GEMM1 out) -> t2 (GEMM2 out, aliased)
    float* t1 = ws + off; off += (size_t)N_NODES * HID;
    float* t2 = t1;
    // Region A: A2 planes (25.6M floats) -> csr_ew + h0/hA/hB (15.2M floats)
    float* regA = ws + off; off += (size_t)N_NODES * HID;
    short* A2hi = (short*)regA;
    short* A2lo = A2hi + (size_t)N_NODES * HID;
    int2*  csr_ew = (int2*)regA;                         // 1.6M int2 = 3.2M floats
    float* h0 = regA + 2 * (size_t)N_EDGES;
    float* hA = h0 + (size_t)N_NODES * OUT_C;
    float* hB = hA + (size_t)N_NODES * OUT_C;

    // --- degree / dinv / offsets ---
    hipMemsetAsync(cnt, 0, N_NODES * sizeof(int), stream);
    deg_count_kernel<<<(N_EDGES + 255) / 256, 256, 0, stream>>>(e_col, cnt, N_EDGES);
    dinv_kernel<<<(N_NODES + 255) / 256, 256, 0, stream>>>(cnt, dinv, N_NODES);
    scan_partial_kernel<<<NBLK_SCAN, 256, 0, stream>>>(cnt, bsum);
    scan_bsum_kernel<<<1, 128, 0, stream>>>(bsum, NBLK_SCAN);
    scan_final_kernel<<<NBLK_SCAN, 256, 0, stream>>>(cnt, bsum, offs);
    set_total_kernel<<<1, 64, 0, stream>>>(offs);

    // --- weight pre-split ---
    wsplit_kernel<<<(256 * K1PAD + 255) / 256, 256, 0, stream>>>(W1, W1hi, W1lo, IN_C, 256, K1PAD);
    wsplit_kernel<<<(256 * K2PAD + 255) / 256, 256, 0, stream>>>(W2, W2hi, W2lo, HID, 256, K2PAD);

    // --- MLP ---
    {
        const int nblk = (N_NODES + GBM - 1) / GBM;   // 1563
        gemm1_fused_kernel<<<nblk, 256, 0, stream>>>(x, W1hi, W1lo, b1, t1, N_NODES);
        layernorm_split_kernel<<<(N_NODES + 3) / 4, 256, 0, stream>>>(t1, g1, be1, A2hi, A2lo, N_NODES);
        gemm2_kernel<<<nblk, 256, 0, stream>>>(A2hi, A2lo, W2hi, W2lo, b2, t2, N_NODES);
        ln_gemm3_kernel<<<(N_NODES + 3) / 4, 256, 0, stream>>>(t2, g2, be2, W3, b3, h0, N_NODES);
    }

    // --- CSR build (A2 planes dead; cnt reused as fill cursor) ---
    hipMemsetAsync(cnt, 0, N_NODES * sizeof(int), stream);
    csr_fill_kernel<<<(N_EDGES + 255) / 256, 256, 0, stream>>>(
        e_row, e_col, dinv, offs, cnt, csr_ew, N_EDGES);

    // --- APPNP: 10 gather steps (proven 10-launch path) ---
    const float* hcur = h0;
    for (int it = 0; it < K_ITERS; it++) {
        float* tgt = (it == K_ITERS - 1) ? out : ((it & 1) ? hB : hA);
        appnp_kernel<<<(N_NODES + 3) / 4, 256, 0, stream>>>(
            offs, csr_ew, dinv, hcur, h0, tgt);
        hcur = tgt;
    }
}

// Round 6
// 1377.606 us; speedup vs baseline: 1.3439x; 1.3439x over previous
//
#include <hip/hip_runtime.h>
#include <hip/hip_bf16.h>
#include <math.h>

#define N_NODES 100000
#define N_EDGES 1600000
#define IN_C    500
#define HID     256
#define OUT_C   40
#define K_ITERS 10
#define ALPHA   0.1f
#define LN_EPS  1e-5f

#define K1PAD   512
#define K2PAD   256

#define SCAN_CHUNK 1024
#define NBLK_SCAN  ((N_NODES + SCAN_CHUNK - 1) / SCAN_CHUNK)   // 98

typedef __attribute__((ext_vector_type(8))) short bf16x8;
typedef __attribute__((ext_vector_type(4))) float f32x4;

// ---------------------------------------------------------------------------
// fp32 -> bf16 hi/lo split (3-term Markidis; lo absorbs truncation error)
// ---------------------------------------------------------------------------
__device__ __forceinline__ void split2(float a, short& hi, short& lo) {
    const unsigned ua = __float_as_uint(a);
    hi = (short)(ua >> 16);
    const float r = a - __uint_as_float(ua & 0xffff0000u);
    lo = (short)(__float_as_uint(r) >> 16);
}

// round-to-nearest-even fp32 -> bf16 (for the APPNP gather mirror)
__device__ __forceinline__ unsigned short rtn_bf16(float f) {
    const unsigned u = __float_as_uint(f);
    return (unsigned short)((u + 0x7FFFu + ((u >> 16) & 1u)) >> 16);
}

__device__ __forceinline__ float bf2f(unsigned short v) {
    return __uint_as_float(((unsigned)v) << 16);
}

__device__ __forceinline__ void async_load16(const void* g, void* l) {
    __builtin_amdgcn_global_load_lds(
        (const __attribute__((address_space(1))) void*)g,
        (__attribute__((address_space(3))) void*)l, 16, 0, 0);
}

// ---------------------------------------------------------------------------
// degree count / dinv
// ---------------------------------------------------------------------------
__global__ void deg_count_kernel(const int* __restrict__ col, int* __restrict__ cnt, int e) {
    int i = blockIdx.x * blockDim.x + threadIdx.x;
    if (i < e) atomicAdd(&cnt[col[i]], 1);
}

__global__ void dinv_kernel(const int* __restrict__ cnt, float* __restrict__ dinv, int n) {
    int i = blockIdx.x * blockDim.x + threadIdx.x;
    if (i < n) dinv[i] = rsqrtf((float)cnt[i] + 1.0f);  // +1 = self loop
}

// ---------------------------------------------------------------------------
// 3-kernel exclusive scan of cnt[N] -> offs[N] (+ offs[N]=E)
// ---------------------------------------------------------------------------
__global__ __launch_bounds__(256) void scan_partial_kernel(const int* __restrict__ cnt,
                                                           int* __restrict__ bsum) {
    __shared__ int s[256];
    const int base = blockIdx.x * SCAN_CHUNK;
    const int t = threadIdx.x;
    int sum = 0;
    #pragma unroll
    for (int j = 0; j < 4; j++) {
        int idx = base + t * 4 + j;
        if (idx < N_NODES) sum += cnt[idx];
    }
    s[t] = sum;
    __syncthreads();
    for (int off = 128; off > 0; off >>= 1) {
        if (t < off) s[t] += s[t + off];
        __syncthreads();
    }
    if (t == 0) bsum[blockIdx.x] = s[0];
}

__global__ __launch_bounds__(128) void scan_bsum_kernel(int* __restrict__ bsum, int nblk) {
    __shared__ int s[128];
    const int t = threadIdx.x;
    const int orig = (t < nblk) ? bsum[t] : 0;
    s[t] = orig;
    __syncthreads();
    for (int off = 1; off < 128; off <<= 1) {
        int v = 0;
        if (t >= off) v = s[t - off];
        __syncthreads();
        s[t] += v;
        __syncthreads();
    }
    if (t < nblk) bsum[t] = s[t] - orig;   // exclusive
}

__global__ __launch_bounds__(256) void scan_final_kernel(const int* __restrict__ cnt,
                                                         const int* __restrict__ bsum,
                                                         int* __restrict__ offs) {
    __shared__ int s[256];
    const int base = blockIdx.x * SCAN_CHUNK;
    const int t = threadIdx.x;
    int v[4];
    int lsum = 0;
    #pragma unroll
    for (int j = 0; j < 4; j++) {
        int idx = base + t * 4 + j;
        v[j] = (idx < N_NODES) ? cnt[idx] : 0;
        lsum += v[j];
    }
    s[t] = lsum;
    __syncthreads();
    const int orig = lsum;
    for (int off = 1; off < 256; off <<= 1) {
        int u = 0;
        if (t >= off) u = s[t - off];
        __syncthreads();
        s[t] += u;
        __syncthreads();
    }
    int run = bsum[blockIdx.x] + (s[t] - orig);
    #pragma unroll
    for (int j = 0; j < 4; j++) {
        int idx = base + t * 4 + j;
        if (idx < N_NODES) offs[idx] = run;
        run += v[j];
    }
}

__global__ void set_total_kernel(int* __restrict__ offs) {
    if (threadIdx.x == 0 && blockIdx.x == 0) offs[N_NODES] = N_EDGES;
}

// ---------------------------------------------------------------------------
// CSR fill: group edges by target col; packed (src, weight-bits) int2
// ---------------------------------------------------------------------------
__global__ void csr_fill_kernel(const int* __restrict__ row, const int* __restrict__ col,
                                const float* __restrict__ dinv, const int* __restrict__ offs,
                                int* __restrict__ cursor, int2* __restrict__ csr_ew, int e) {
    int i = blockIdx.x * blockDim.x + threadIdx.x;
    if (i >= e) return;
    const int r = row[i], c = col[i];
    const int p = offs[c] + atomicAdd(&cursor[c], 1);
    csr_ew[p] = make_int2(r, __float_as_int(dinv[r] * dinv[c]));
}

// ---------------------------------------------------------------------------
// W [K,N] fp32 -> transposed hi/lo planes [N,Kpad]
// ---------------------------------------------------------------------------
__global__ __launch_bounds__(256) void wsplit_kernel(
    const float* __restrict__ W, short* __restrict__ hi, short* __restrict__ lo,
    int K, int Nn, int Kpad)
{
    const int idx = blockIdx.x * 256 + threadIdx.x;
    if (idx >= Nn * Kpad) return;
    const int n = idx / Kpad, k = idx - n * Kpad;
    const float v = (k < K) ? W[(size_t)k * Nn + n] : 0.0f;
    short h, l;
    split2(v, h, l);
    hi[idx] = h;
    lo[idx] = l;
}

// ---------------------------------------------------------------------------
// GEMM1 (proven r1/r3 staged version, 228us): fused A-split, B planes
// async-staged, 64x256 tile, double-buffered, 1 barrier/K-step, XOR swizzle.
// Register-direct variant (r5) was 2.2x WORSE: B loads at 1KB stride
// un-coalesce into 16-line gathers. LDS staging IS the coalescing machinery.
// ---------------------------------------------------------------------------
#define GBM 64
#define GBN 256
#define GBK 32
#define NSTEP1 (K1PAD / GBK)   // 16
#define NSTEP2 (K2PAD / GBK)   // 8

__global__ __launch_bounds__(256, 2) void gemm1_fused_kernel(
    const float* __restrict__ X,
    const short* __restrict__ Bhi, const short* __restrict__ Blo,
    const float* __restrict__ bias, float* __restrict__ C, int M)
{
    __shared__ short As[2][2][GBM * GBK];   // [buf][plane] 16 KB
    __shared__ short Bs[2][2][GBN * GBK];   // [buf][plane] 64 KB

    const int tid  = threadIdx.x;
    const int wid  = tid >> 6, lane = tid & 63;
    const int wm   = wid >> 1, wn = wid & 1;
    const int fm   = lane & 15, fq = lane >> 4;
    const int row0 = blockIdx.x * GBM;

    const int ar   = tid >> 2;          // staged A row 0..63
    const int aseg = tid & 3;           // 8-float segment
    const int gr   = min(row0 + ar, M - 1);
    const int asw  = (aseg ^ ((ar >> 1) & 3)) * 8;   // swizzled write k-offset

    f32x4 acc[2][8] = {};

    auto stageB = [&](int ks, int buf) {
        const int k0 = ks * GBK;
        #pragma unroll
        for (int i = 0; i < 4; i++) {
            const int c  = i * 256 + tid;
            const int n  = c >> 2;
            const int k8 = ((c & 3) ^ ((n >> 1) & 3)) * 8;  // pre-swizzled source
            const int cb = (i * 256 + wid * 64) * 8;        // wave-uniform LDS base
            const size_t oB = (size_t)n * K1PAD + k0 + k8;
            async_load16(Bhi + oB, &Bs[buf][0][cb]);
            async_load16(Blo + oB, &Bs[buf][1][cb]);
        }
    };
    auto loadX = [&](int ks, float* v) {
        const int kb = ks * GBK + aseg * 8;
        if (kb + 8 <= IN_C) {
            const float4 v0 = *(const float4*)(X + (size_t)gr * IN_C + kb);
            const float4 v1 = *(const float4*)(X + (size_t)gr * IN_C + kb + 4);
            v[0]=v0.x; v[1]=v0.y; v[2]=v0.z; v[3]=v0.w;
            v[4]=v1.x; v[5]=v1.y; v[6]=v1.z; v[7]=v1.w;
        } else {
            #pragma unroll
            for (int j = 0; j < 8; j++)
                v[j] = (kb + j < IN_C) ? X[(size_t)gr * IN_C + kb + j] : 0.0f;
        }
    };
    auto writeA = [&](const float* v, int buf) {
        bf16x8 h8, l8;
        #pragma unroll
        for (int j = 0; j < 8; j++) { short th, tl; split2(v[j], th, tl); h8[j] = th; l8[j] = tl; }
        *(bf16x8*)&As[buf][0][ar * GBK + asw] = h8;
        *(bf16x8*)&As[buf][1][ar * GBK + asw] = l8;
    };
    auto compute = [&](int buf) {
        bf16x8 ah[2], al[2];
        #pragma unroll
        for (int tm = 0; tm < 2; tm++) {
            const int r   = wm * 32 + tm * 16 + fm;
            const int ks8 = (fq ^ ((r >> 1) & 3)) * 8;
            ah[tm] = *(const bf16x8*)&As[buf][0][r * GBK + ks8];
            al[tm] = *(const bf16x8*)&As[buf][1][r * GBK + ks8];
        }
        #pragma unroll
        for (int tn = 0; tn < 8; tn++) {
            const int cc  = wn * 128 + tn * 16 + fm;
            const int ks8 = (fq ^ ((cc >> 1) & 3)) * 8;
            const bf16x8 bh = *(const bf16x8*)&Bs[buf][0][cc * GBK + ks8];
            const bf16x8 bl = *(const bf16x8*)&Bs[buf][1][cc * GBK + ks8];
            #pragma unroll
            for (int tm = 0; tm < 2; tm++) {
                acc[tm][tn] = __builtin_amdgcn_mfma_f32_16x16x32_bf16(ah[tm], bh, acc[tm][tn], 0, 0, 0);
                acc[tm][tn] = __builtin_amdgcn_mfma_f32_16x16x32_bf16(ah[tm], bl, acc[tm][tn], 0, 0, 0);
                acc[tm][tn] = __builtin_amdgcn_mfma_f32_16x16x32_bf16(al[tm], bh, acc[tm][tn], 0, 0, 0);
            }
        }
    };

    float xvA[8], xvB[8];
    loadX(0, xvA);
    stageB(0, 0);
    loadX(1, xvB);
    writeA(xvA, 0);
    __syncthreads();

    #pragma unroll
    for (int ks = 0; ks < NSTEP1; ks += 2) {
        if (ks + 1 < NSTEP1) stageB(ks + 1, 1);
        if (ks + 2 < NSTEP1) loadX(ks + 2, xvA);
        compute(0);
        if (ks + 1 < NSTEP1) writeA(xvB, 1);
        __syncthreads();
        if (ks + 1 < NSTEP1) {
            if (ks + 2 < NSTEP1) stageB(ks + 2, 0);
            if (ks + 3 < NSTEP1) loadX(ks + 3, xvB);
            compute(1);
            if (ks + 2 < NSTEP1) writeA(xvA, 0);
            __syncthreads();
        }
    }

    #pragma unroll
    for (int tm = 0; tm < 2; tm++) {
        #pragma unroll
        for (int tn = 0; tn < 8; tn++) {
            const int gc = wn * 128 + tn * 16 + fm;
            const float bv = bias[gc];
            #pragma unroll
            for (int r = 0; r < 4; r++) {
                const int gr2 = row0 + wm * 32 + tm * 16 + fq * 4 + r;
                if (gr2 < M) {
                    float v = acc[tm][tn][r] + bv;
                    v = 0.5f * v * (1.0f + erff(v * 0.70710678118654752f));
                    C[(size_t)gr2 * 256 + gc] = v;
                }
            }
        }
    }
}

// ---------------------------------------------------------------------------
// GEMM2 (proven r1/r3 staged version): all-async staging, double-buffered.
// ---------------------------------------------------------------------------
__global__ __launch_bounds__(256, 2) void gemm2_kernel(
    const short* __restrict__ Ahi, const short* __restrict__ Alo,
    const short* __restrict__ Bhi, const short* __restrict__ Blo,
    const float* __restrict__ bias, float* __restrict__ C, int M)
{
    __shared__ short As[2][2][GBM * GBK];
    __shared__ short Bs[2][2][GBN * GBK];

    const int tid  = threadIdx.x;
    const int wid  = tid >> 6, lane = tid & 63;
    const int wm   = wid >> 1, wn = wid & 1;
    const int fm   = lane & 15, fq = lane >> 4;
    const int row0 = blockIdx.x * GBM;

    f32x4 acc[2][8] = {};

    auto stage = [&](int ks, int buf) {
        const int k0 = ks * GBK;
        {
            const int m  = tid >> 2;
            const int k8 = ((tid & 3) ^ ((m >> 1) & 3)) * 8;   // pre-swizzled source
            const int cb = (wid * 64) * 8;
            const size_t oA = (size_t)min(row0 + m, M - 1) * K2PAD + k0 + k8;
            async_load16(Ahi + oA, &As[buf][0][cb]);
            async_load16(Alo + oA, &As[buf][1][cb]);
        }
        #pragma unroll
        for (int i = 0; i < 4; i++) {
            const int c  = i * 256 + tid;
            const int n  = c >> 2;
            const int k8 = ((c & 3) ^ ((n >> 1) & 3)) * 8;
            const int cb = (i * 256 + wid * 64) * 8;
            const size_t oB = (size_t)n * K2PAD + k0 + k8;
            async_load16(Bhi + oB, &Bs[buf][0][cb]);
            async_load16(Blo + oB, &Bs[buf][1][cb]);
        }
    };
    auto compute = [&](int buf) {
        bf16x8 ah[2], al[2];
        #pragma unroll
        for (int tm = 0; tm < 2; tm++) {
            const int r   = wm * 32 + tm * 16 + fm;
            const int ks8 = (fq ^ ((r >> 1) & 3)) * 8;
            ah[tm] = *(const bf16x8*)&As[buf][0][r * GBK + ks8];
            al[tm] = *(const bf16x8*)&As[buf][1][r * GBK + ks8];
        }
        #pragma unroll
        for (int tn = 0; tn < 8; tn++) {
            const int cc  = wn * 128 + tn * 16 + fm;
            const int ks8 = (fq ^ ((cc >> 1) & 3)) * 8;
            const bf16x8 bh = *(const bf16x8*)&Bs[buf][0][cc * GBK + ks8];
            const bf16x8 bl = *(const bf16x8*)&Bs[buf][1][cc * GBK + ks8];
            #pragma unroll
            for (int tm = 0; tm < 2; tm++) {
                acc[tm][tn] = __builtin_amdgcn_mfma_f32_16x16x32_bf16(ah[tm], bh, acc[tm][tn], 0, 0, 0);
                acc[tm][tn] = __builtin_amdgcn_mfma_f32_16x16x32_bf16(ah[tm], bl, acc[tm][tn], 0, 0, 0);
                acc[tm][tn] = __builtin_amdgcn_mfma_f32_16x16x32_bf16(al[tm], bh, acc[tm][tn], 0, 0, 0);
            }
        }
    };

    stage(0, 0);
    __syncthreads();

    #pragma unroll
    for (int ks = 0; ks < NSTEP2; ks += 2) {
        if (ks + 1 < NSTEP2) stage(ks + 1, 1);
        compute(0);
        __syncthreads();
        if (ks + 1 < NSTEP2) {
            if (ks + 2 < NSTEP2) stage(ks + 2, 0);
            compute(1);
            __syncthreads();
        }
    }

    #pragma unroll
    for (int tm = 0; tm < 2; tm++) {
        #pragma unroll
        for (int tn = 0; tn < 8; tn++) {
            const int gc = wn * 128 + tn * 16 + fm;
            const float bv = bias[gc];
            #pragma unroll
            for (int r = 0; r < 4; r++) {
                const int gr2 = row0 + wm * 32 + tm * 16 + fq * 4 + r;
                if (gr2 < M) {
                    float v = acc[tm][tn][r] + bv;
                    v = 0.5f * v * (1.0f + erff(v * 0.70710678118654752f));
                    C[(size_t)gr2 * 256 + gc] = v;
                }
            }
        }
    }
}

// ---------------------------------------------------------------------------
// LayerNorm(256) -> bf16 hi/lo planes [M,256] (feeds GEMM2)
// ---------------------------------------------------------------------------
__global__ __launch_bounds__(256) void layernorm_split_kernel(
    const float* __restrict__ h, const float* __restrict__ g, const float* __restrict__ b,
    short* __restrict__ hi, short* __restrict__ lo, int nrows)
{
    const int wave = threadIdx.x >> 6;
    const int lane = threadIdx.x & 63;
    const int row  = blockIdx.x * 4 + wave;
    if (row >= nrows) return;

    const float* p = h + (size_t)row * HID;
    float v[4];
    float s = 0.0f;
    #pragma unroll
    for (int j = 0; j < 4; j++) { v[j] = p[lane + 64 * j]; s += v[j]; }
    #pragma unroll
    for (int off = 32; off > 0; off >>= 1) s += __shfl_xor(s, off);
    const float mu = s * (1.0f / 256.0f);

    float vs = 0.0f;
    #pragma unroll
    for (int j = 0; j < 4; j++) { float d = v[j] - mu; vs += d * d; }
    #pragma unroll
    for (int off = 32; off > 0; off >>= 1) vs += __shfl_xor(vs, off);
    const float rs = rsqrtf(vs * (1.0f / 256.0f) + LN_EPS);

    #pragma unroll
    for (int j = 0; j < 4; j++) {
        const int c = lane + 64 * j;
        const float o = (v[j] - mu) * rs * g[c] + b[c];
        short th, tl;
        split2(o, th, tl);
        hi[(size_t)row * HID + c] = th;
        lo[(size_t)row * HID + c] = tl;
    }
}

// ---------------------------------------------------------------------------
// Fused LayerNorm(256) + GEMM3 [256 x 40] + b3 -> h0 (fp32) + h0b (bf16
// gather mirror for APPNP).
// ---------------------------------------------------------------------------
__global__ __launch_bounds__(256) void ln_gemm3_kernel(
    const float* __restrict__ h, const float* __restrict__ g, const float* __restrict__ b,
    const float* __restrict__ W, const float* __restrict__ bias,
    float* __restrict__ C, unsigned short* __restrict__ Cb, int nrows)
{
    __shared__ float Ws[HID * OUT_C];   // 40 KB
    __shared__ float bs[OUT_C];
    __shared__ float rowbuf[4][HID];    // 4 KB

    for (int i = threadIdx.x; i < HID * OUT_C; i += 256) Ws[i] = W[i];
    if (threadIdx.x < OUT_C) bs[threadIdx.x] = bias[threadIdx.x];

    const int wave = threadIdx.x >> 6;
    const int lane = threadIdx.x & 63;
    const int row  = blockIdx.x * 4 + wave;
    const bool alive = (row < nrows);

    if (alive) {
        const float* p = h + (size_t)row * HID;
        float v[4];
        float s = 0.0f;
        #pragma unroll
        for (int j = 0; j < 4; j++) { v[j] = p[lane + 64 * j]; s += v[j]; }
        #pragma unroll
        for (int off = 32; off > 0; off >>= 1) s += __shfl_xor(s, off);
        const float mu = s * (1.0f / 256.0f);

        float vs = 0.0f;
        #pragma unroll
        for (int j = 0; j < 4; j++) { float d = v[j] - mu; vs += d * d; }
        #pragma unroll
        for (int off = 32; off > 0; off >>= 1) vs += __shfl_xor(vs, off);
        const float rs = rsqrtf(vs * (1.0f / 256.0f) + LN_EPS);

        #pragma unroll
        for (int j = 0; j < 4; j++) {
            const int c = lane + 64 * j;
            rowbuf[wave][c] = (v[j] - mu) * rs * g[c] + b[c];
        }
    }
    __syncthreads();   // Ws + rowbuf ready

    if (alive && lane < OUT_C) {
        float s = 0.0f;
        #pragma unroll 8
        for (int k = 0; k < HID; k++)
            s += rowbuf[wave][k] * Ws[k * OUT_C + lane];
        const float o = s + bs[lane];
        C [(size_t)row * OUT_C + lane] = o;
        Cb[(size_t)row * OUT_C + lane] = rtn_bf16(o);
    }
}

// ---------------------------------------------------------------------------
// APPNP step v3: gather payload in bf16 (80B/row -> always 2 cache lines
// = 128B/edge vs fp32's 192B/edge). Theory: APPNP is L3-BW-bound at line
// granularity (3-wide ILP change was neutral -> not latency-bound). The
// fp32 chain (self-term, h0, stored h) stays full precision; bf16 error
// enters only via the weighted neighbor sum (~1e-3/step, incoherent).
// Each step writes fp32 tgt + bf16 mirror tgtb (8MB, noise).
// ---------------------------------------------------------------------------
__global__ __launch_bounds__(256) void appnp_kernel(
    const int* __restrict__ offs, const int2* __restrict__ csr_ew,
    const float* __restrict__ dinv,
    const float* __restrict__ h, const unsigned short* __restrict__ hb,
    const float* __restrict__ h0,
    float* __restrict__ out, unsigned short* __restrict__ outb)
{
    const int node = blockIdx.x * 4 + (threadIdx.x >> 6);
    if (node >= N_NODES) return;           // wave-uniform exit
    const int lane = threadIdx.x & 63;
    const int g = lane / 10;               // 0..6 (g==6 => lanes 60..63 idle)
    const int q = lane - g * 10;           // channel quad 0..9
    const bool act = (lane < 60);

    const int start = offs[node];
    const int end   = offs[node + 1];

    const float d = dinv[node];
    float4 hs  = make_float4(0.f, 0.f, 0.f, 0.f);
    float4 h0v = make_float4(0.f, 0.f, 0.f, 0.f);
    const size_t eidx = (size_t)node * OUT_C + (lane < 10 ? lane : 0) * 4;
    if (lane < 10) {
        hs  = *(const float4*)(h + eidx);
        h0v = *(const float4*)(h0 + eidx);
    }

    float ax = 0.0f, ay = 0.0f, az = 0.0f, aw = 0.0f;
    for (int e0 = start; e0 < end; e0 += 18) {
        const int ee0 = e0 + g, ee1 = ee0 + 6, ee2 = ee0 + 12;
        const bool a0 = act && (ee0 < end);
        const bool a1 = act && (ee1 < end);
        const bool a2 = act && (ee2 < end);
        const int2 ed0 = csr_ew[a0 ? ee0 : start];
        const int2 ed1 = csr_ew[a1 ? ee1 : start];
        const int2 ed2 = csr_ew[a2 ? ee2 : start];
        const ushort4 u0 = *(const ushort4*)(hb + (size_t)ed0.x * OUT_C + q * 4);
        const ushort4 u1 = *(const ushort4*)(hb + (size_t)ed1.x * OUT_C + q * 4);
        const ushort4 u2 = *(const ushort4*)(hb + (size_t)ed2.x * OUT_C + q * 4);
        const float w0 = a0 ? __int_as_float(ed0.y) : 0.0f;
        const float w1 = a1 ? __int_as_float(ed1.y) : 0.0f;
        const float w2 = a2 ? __int_as_float(ed2.y) : 0.0f;
        ax += w0 * bf2f(u0.x) + w1 * bf2f(u1.x) + w2 * bf2f(u2.x);
        ay += w0 * bf2f(u0.y) + w1 * bf2f(u1.y) + w2 * bf2f(u2.y);
        az += w0 * bf2f(u0.z) + w1 * bf2f(u1.z) + w2 * bf2f(u2.z);
        aw += w0 * bf2f(u0.w) + w1 * bf2f(u1.w) + w2 * bf2f(u2.w);
    }

    // reduce over edge-groups: lanes {q, q+10, ..., q+50} -> lane q
    ax += __shfl(ax, lane + 30); ay += __shfl(ay, lane + 30);
    az += __shfl(az, lane + 30); aw += __shfl(aw, lane + 30);
    {
        const float bx = __shfl(ax, lane + 10), cx = __shfl(ax, lane + 20);
        const float by = __shfl(ay, lane + 10), cy = __shfl(ay, lane + 20);
        const float bz = __shfl(az, lane + 10), cz = __shfl(az, lane + 20);
        const float bw = __shfl(aw, lane + 10), cw = __shfl(aw, lane + 20);
        ax += bx + cx; ay += by + cy; az += bz + cz; aw += bw + cw;
    }

    if (lane < 10) {
        const float self = d * d;
        float4 o;
        o.x = (1.0f - ALPHA) * (ax + self * hs.x) + ALPHA * h0v.x;
        o.y = (1.0f - ALPHA) * (ay + self * hs.y) + ALPHA * h0v.y;
        o.z = (1.0f - ALPHA) * (az + self * hs.z) + ALPHA * h0v.z;
        o.w = (1.0f - ALPHA) * (aw + self * hs.w) + ALPHA * h0v.w;
        *(float4*)(out + eidx) = o;
        ushort4 ob;
        ob.x = rtn_bf16(o.x); ob.y = rtn_bf16(o.y);
        ob.z = rtn_bf16(o.z); ob.w = rtn_bf16(o.w);
        *(ushort4*)(outb + eidx) = ob;
    }
}

// ---------------------------------------------------------------------------
extern "C" void kernel_launch(void* const* d_in, const int* in_sizes, int n_in,
                              void* d_out, int out_size, void* d_ws, size_t ws_size,
                              hipStream_t stream) {
    const float* x   = (const float*)d_in[0];
    const int*   ei  = (const int*)d_in[1];
    const float* W1  = (const float*)d_in[2];
    const float* b1  = (const float*)d_in[3];
    const float* g1  = (const float*)d_in[4];
    const float* be1 = (const float*)d_in[5];
    const float* W2  = (const float*)d_in[6];
    const float* b2  = (const float*)d_in[7];
    const float* g2  = (const float*)d_in[8];
    const float* be2 = (const float*)d_in[9];
    const float* W3  = (const float*)d_in[10];
    const float* b3  = (const float*)d_in[11];
    float* out = (float*)d_out;

    const int* e_row = ei;
    const int* e_col = ei + N_EDGES;

    // ---- workspace layout (float units), regions aliased by liveness ----
    float* ws = (float*)d_ws;
    size_t off = 0;
    float* dinv = ws + off; off += N_NODES;
    int*   cnt  = (int*)(ws + off); off += N_NODES;
    int*   offs = (int*)(ws + off); off += N_NODES + 1;
    int*   bsum = (int*)(ws + off); off += 128 + 3;      // +3: keep 16B alignment downstream
    short* W1hi = (short*)(ws + off); off += 65536;      // 256*512 shorts
    short* W1lo = (short*)(ws + off); off += 65536;
    short* W2hi = (short*)(ws + off); off += 32768;      // 256*256 shorts
    short* W2lo = (short*)(ws + off); off += 32768;
    // Region B: t1 (GEMM1 out) -> t2 (GEMM2 out, aliased)
    float* t1 = ws + off; off += (size_t)N_NODES * HID;
    float* t2 = t1;
    // Region A: A2 planes (25.6M floats) -> csr_ew + h0/hA/hB + bf16 mirrors
    float* regA = ws + off; off += (size_t)N_NODES * HID;
    short* A2hi = (short*)regA;
    short* A2lo = A2hi + (size_t)N_NODES * HID;
    int2*  csr_ew = (int2*)regA;                         // 1.6M int2 = 3.2M floats
    float* h0 = regA + 2 * (size_t)N_EDGES;
    float* hA = h0 + (size_t)N_NODES * OUT_C;
    float* hB = hA + (size_t)N_NODES * OUT_C;
    // bf16 gather mirrors (3 x 4M shorts = 6M floats; region A total 21.2M < 25.6M)
    unsigned short* h0b = (unsigned short*)(hB + (size_t)N_NODES * OUT_C);
    unsigned short* hAb = h0b + (size_t)N_NODES * OUT_C;
    unsigned short* hBb = hAb + (size_t)N_NODES * OUT_C;

    // --- degree / dinv / offsets ---
    hipMemsetAsync(cnt, 0, N_NODES * sizeof(int), stream);
    deg_count_kernel<<<(N_EDGES + 255) / 256, 256, 0, stream>>>(e_col, cnt, N_EDGES);
    dinv_kernel<<<(N_NODES + 255) / 256, 256, 0, stream>>>(cnt, dinv, N_NODES);
    scan_partial_kernel<<<NBLK_SCAN, 256, 0, stream>>>(cnt, bsum);
    scan_bsum_kernel<<<1, 128, 0, stream>>>(bsum, NBLK_SCAN);
    scan_final_kernel<<<NBLK_SCAN, 256, 0, stream>>>(cnt, bsum, offs);
    set_total_kernel<<<1, 64, 0, stream>>>(offs);

    // --- weight pre-split ---
    wsplit_kernel<<<(256 * K1PAD + 255) / 256, 256, 0, stream>>>(W1, W1hi, W1lo, IN_C, 256, K1PAD);
    wsplit_kernel<<<(256 * K2PAD + 255) / 256, 256, 0, stream>>>(W2, W2hi, W2lo, HID, 256, K2PAD);

    // --- MLP ---
    {
        const int nblk = (N_NODES + GBM - 1) / GBM;   // 1563
        gemm1_fused_kernel<<<nblk, 256, 0, stream>>>(x, W1hi, W1lo, b1, t1, N_NODES);
        layernorm_split_kernel<<<(N_NODES + 3) / 4, 256, 0, stream>>>(t1, g1, be1, A2hi, A2lo, N_NODES);
        gemm2_kernel<<<nblk, 256, 0, stream>>>(A2hi, A2lo, W2hi, W2lo, b2, t2, N_NODES);
        ln_gemm3_kernel<<<(N_NODES + 3) / 4, 256, 0, stream>>>(t2, g2, be2, W3, b3, h0, h0b, N_NODES);
    }

    // --- CSR build (A2 planes dead; cnt reused as fill cursor) ---
    hipMemsetAsync(cnt, 0, N_NODES * sizeof(int), stream);
    csr_fill_kernel<<<(N_EDGES + 255) / 256, 256, 0, stream>>>(
        e_row, e_col, dinv, offs, cnt, csr_ew, N_EDGES);

    // --- APPNP: 10 gather steps, bf16 gather payload ---
    const float* hcur = h0;
    const unsigned short* hcurb = h0b;
    for (int it = 0; it < K_ITERS; it++) {
        float* tgt = (it == K_ITERS - 1) ? out : ((it & 1) ? hB : hA);
        unsigned short* tgtb = (it & 1) ? hBb : hAb;
        appnp_kernel<<<(N_NODES + 3) / 4, 256, 0, stream>>>(
            offs, csr_ew, dinv, hcur, hcurb, h0, tgt, tgtb);
        hcur = tgt;
        hcurb = tgtb;
    }
}